// Round 1
// baseline (742.525 us; speedup 1.0000x reference)
//
#include <hip/hip_runtime.h>
#include <hip/hip_bf16.h>

// GCN: 3-layer GraphConv (DGL norm='both') on N=100000 nodes, E=1600000 edges.
// Strategy R1: correct fp32 skeleton.
//   - degrees via int atomics; norms = rsqrt(max(deg,1))
//   - CSR (sorted by dst) built on-device once per call: histogram + 2-level scan + scatter
//   - per-layer: hw = (h * src_norm) @ W   (fp32 tiled GEMM)
//                h' = act(agg(hw) * dst_norm + b)   (gather-sum over CSR, no float atomics)

constexpr int BLK = 256;

// ---------------- degree / norm ----------------
__global__ void k_degrees(const int* __restrict__ src, const int* __restrict__ dst,
                          int* __restrict__ outdeg, int* __restrict__ indeg, int E) {
    int e = blockIdx.x * blockDim.x + threadIdx.x;
    if (e < E) {
        atomicAdd(&outdeg[src[e]], 1);
        atomicAdd(&indeg[dst[e]], 1);
    }
}

__global__ void k_norms(const int* __restrict__ outdeg, const int* __restrict__ indeg,
                        float* __restrict__ srcn, float* __restrict__ dstn, int N) {
    int i = blockIdx.x * blockDim.x + threadIdx.x;
    if (i < N) {
        int od = outdeg[i]; if (od < 1) od = 1;
        int id = indeg[i];  if (id < 1) id = 1;
        srcn[i] = rsqrtf((float)od);
        dstn[i] = rsqrtf((float)id);
    }
}

// ---------------- CSR build: blocksum -> scan(bsum) -> local scan+scatter -> fill ----------------
__global__ void k_blocksum(const int* __restrict__ counts, int* __restrict__ bsum, int N) {
    __shared__ int sdata[BLK];
    int i = blockIdx.x * BLK + threadIdx.x;
    sdata[threadIdx.x] = (i < N) ? counts[i] : 0;
    __syncthreads();
    for (int s = BLK / 2; s > 0; s >>= 1) {
        if (threadIdx.x < s) sdata[threadIdx.x] += sdata[threadIdx.x + s];
        __syncthreads();
    }
    if (threadIdx.x == 0) bsum[blockIdx.x] = sdata[0];
}

__global__ void k_scan_bsum(const int* __restrict__ bsum, int* __restrict__ bscan, int nb) {
    // one block of 512 threads; nb <= 512
    __shared__ int s[512];
    int t = threadIdx.x;
    s[t] = (t < nb) ? bsum[t] : 0;
    __syncthreads();
    for (int d = 1; d < 512; d <<= 1) {
        int x = (t >= d) ? s[t - d] : 0;
        __syncthreads();
        s[t] += x;
        __syncthreads();
    }
    bscan[t] = (t > 0) ? s[t - 1] : 0;
}

__global__ void k_scan_scatter(const int* __restrict__ counts, const int* __restrict__ bscan,
                               int* __restrict__ rowptr, int* __restrict__ cursor, int N) {
    __shared__ int s[BLK];
    int i = blockIdx.x * BLK + threadIdx.x;
    int c = (i < N) ? counts[i] : 0;
    s[threadIdx.x] = c;
    __syncthreads();
    for (int d = 1; d < BLK; d <<= 1) {
        int x = (threadIdx.x >= d) ? s[threadIdx.x - d] : 0;
        __syncthreads();
        s[threadIdx.x] += x;
        __syncthreads();
    }
    if (i < N) {
        int excl = bscan[blockIdx.x] + s[threadIdx.x] - c;
        rowptr[i] = excl;
        cursor[i] = excl;
        if (i == N - 1) rowptr[N] = excl + c;  // == E
    }
}

__global__ void k_fill_csr(const int* __restrict__ src, const int* __restrict__ dst,
                           int* __restrict__ cursor, int* __restrict__ csr_src, int E) {
    int e = blockIdx.x * blockDim.x + threadIdx.x;
    if (e < E) {
        int p = atomicAdd(&cursor[dst[e]], 1);
        csr_src[p] = src[e];
    }
}

// ---------------- GEMM: C[M x 128] = (A[M x 128] * srcn[row]) @ W[128 x 128] ----------------
__global__ __launch_bounds__(256) void k_gemm128(const float* __restrict__ A, const float* __restrict__ W,
                                                 const float* __restrict__ srcn, float* __restrict__ C, int M) {
    __shared__ float As[64][32];
    __shared__ float Ws[32][128];
    int tx = threadIdx.x;
    int row0 = blockIdx.x * 64;
    int r0 = (tx >> 4) * 4;   // 0..60
    int c0 = (tx & 15) * 8;   // 0..120
    float acc[4][8];
#pragma unroll
    for (int i = 0; i < 4; i++)
#pragma unroll
        for (int j = 0; j < 8; j++) acc[i][j] = 0.f;

    for (int kc = 0; kc < 4; ++kc) {
        // A chunk: 64 rows x 32 cols = 512 float4; 2 per thread; scale by src_norm on load
#pragma unroll
        for (int l = 0; l < 2; l++) {
            int f = tx + l * 256;
            int ar = f >> 3;
            int ac = (f & 7) * 4;
            int grow = row0 + ar;
            float4 v = make_float4(0.f, 0.f, 0.f, 0.f);
            if (grow < M) {
                v = *(const float4*)(A + (size_t)grow * 128 + kc * 32 + ac);
                float s = srcn[grow];
                v.x *= s; v.y *= s; v.z *= s; v.w *= s;
            }
            *(float4*)(&As[ar][ac]) = v;
        }
        // W chunk: 32 rows x 128 cols = 1024 float4; 4 per thread
#pragma unroll
        for (int l = 0; l < 4; l++) {
            int f = tx + l * 256;
            int wr = f >> 5;
            int wc = (f & 31) * 4;
            *(float4*)(&Ws[wr][wc]) = *(const float4*)(W + (size_t)(kc * 32 + wr) * 128 + wc);
        }
        __syncthreads();
#pragma unroll
        for (int kk = 0; kk < 32; ++kk) {
            float a0 = As[r0 + 0][kk], a1 = As[r0 + 1][kk], a2 = As[r0 + 2][kk], a3 = As[r0 + 3][kk];
            float4 w0 = *(float4*)(&Ws[kk][c0]);
            float4 w1 = *(float4*)(&Ws[kk][c0 + 4]);
            float wv[8] = {w0.x, w0.y, w0.z, w0.w, w1.x, w1.y, w1.z, w1.w};
#pragma unroll
            for (int j = 0; j < 8; j++) {
                acc[0][j] += a0 * wv[j];
                acc[1][j] += a1 * wv[j];
                acc[2][j] += a2 * wv[j];
                acc[3][j] += a3 * wv[j];
            }
        }
        __syncthreads();
    }
#pragma unroll
    for (int i = 0; i < 4; i++) {
        int grow = row0 + r0 + i;
        if (grow < M) {
            float4 o0 = make_float4(acc[i][0], acc[i][1], acc[i][2], acc[i][3]);
            float4 o1 = make_float4(acc[i][4], acc[i][5], acc[i][6], acc[i][7]);
            *(float4*)(C + (size_t)grow * 128 + c0) = o0;
            *(float4*)(C + (size_t)grow * 128 + c0 + 4) = o1;
        }
    }
}

// ---------------- GEMM small: C[M x 16] = (A[M x 128] * srcn) @ W[128 x 16] ----------------
__global__ __launch_bounds__(256) void k_gemm16(const float* __restrict__ A, const float* __restrict__ W,
                                                const float* __restrict__ srcn, float* __restrict__ C, int M) {
    __shared__ float Ws[128][16];
    __shared__ float As[128][32];
    int tx = threadIdx.x;
    int row0 = blockIdx.x * 128;
#pragma unroll
    for (int l = 0; l < 2; l++) {          // whole W2: 2048 floats = 512 float4
        int f = tx + l * 256;
        int wr = f >> 2;
        int wc = (f & 3) * 4;
        *(float4*)(&Ws[wr][wc]) = *(const float4*)(W + wr * 16 + wc);
    }
    int c = tx & 15;
    int r0 = (tx >> 4) * 8;
    float acc[8];
#pragma unroll
    for (int i = 0; i < 8; i++) acc[i] = 0.f;

    for (int kc = 0; kc < 4; ++kc) {
        __syncthreads();   // covers Ws (first iter) and As reuse (later iters)
#pragma unroll
        for (int l = 0; l < 4; l++) {      // A chunk 128x32 = 1024 float4
            int f = tx + l * 256;
            int ar = f >> 3;
            int ac = (f & 7) * 4;
            int grow = row0 + ar;
            float4 v = make_float4(0.f, 0.f, 0.f, 0.f);
            if (grow < M) {
                v = *(const float4*)(A + (size_t)grow * 128 + kc * 32 + ac);
                float s = srcn[grow];
                v.x *= s; v.y *= s; v.z *= s; v.w *= s;
            }
            *(float4*)(&As[ar][ac]) = v;
        }
        __syncthreads();
#pragma unroll
        for (int kk = 0; kk < 32; ++kk) {
            float w = Ws[kc * 32 + kk][c];
#pragma unroll
            for (int i = 0; i < 8; i++) acc[i] += As[r0 + i][kk] * w;
        }
    }
#pragma unroll
    for (int i = 0; i < 8; i++) {
        int grow = row0 + r0 + i;
        if (grow < M) C[(size_t)grow * 16 + c] = acc[i];
    }
}

// ---------------- aggregation: out[v] = act(sum_{e in in(v)} hw[src[e]] * dstn[v] + b) ----------------
template <int ACT>  // 0 = relu
__global__ __launch_bounds__(256) void k_agg128(const float* __restrict__ hw, const int* __restrict__ rowptr,
                                                const int* __restrict__ csr_src, const float* __restrict__ dstn,
                                                const float* __restrict__ bias, float* __restrict__ out, int N) {
    int w = (blockIdx.x * blockDim.x + threadIdx.x) >> 6;  // node = wave id
    int lane = threadIdx.x & 63;
    if (w >= N) return;
    int beg = rowptr[w], end = rowptr[w + 1];
    float ax = 0.f, ay = 0.f;
    int e = beg;
    for (; e + 4 <= end; e += 4) {   // unroll-4 to overlap idx->row load chains
        int s0 = csr_src[e], s1 = csr_src[e + 1], s2 = csr_src[e + 2], s3 = csr_src[e + 3];
        float2 v0 = *(const float2*)(hw + (size_t)s0 * 128 + lane * 2);
        float2 v1 = *(const float2*)(hw + (size_t)s1 * 128 + lane * 2);
        float2 v2 = *(const float2*)(hw + (size_t)s2 * 128 + lane * 2);
        float2 v3 = *(const float2*)(hw + (size_t)s3 * 128 + lane * 2);
        ax += v0.x + v1.x + v2.x + v3.x;
        ay += v0.y + v1.y + v2.y + v3.y;
    }
    for (; e < end; ++e) {
        int s = csr_src[e];
        float2 v = *(const float2*)(hw + (size_t)s * 128 + lane * 2);
        ax += v.x; ay += v.y;
    }
    float dn = dstn[w];
    float o0 = ax * dn + bias[lane * 2];
    float o1 = ay * dn + bias[lane * 2 + 1];
    if (ACT == 0) { o0 = fmaxf(o0, 0.f); o1 = fmaxf(o1, 0.f); }
    *(float2*)(out + (size_t)w * 128 + lane * 2) = make_float2(o0, o1);
}

__global__ __launch_bounds__(256) void k_agg16(const float* __restrict__ hw, const int* __restrict__ rowptr,
                                               const int* __restrict__ csr_src, const float* __restrict__ dstn,
                                               const float* __restrict__ bias, float* __restrict__ out, int N) {
    int t = blockIdx.x * blockDim.x + threadIdx.x;
    int v = t >> 4; int f = t & 15;
    if (v >= N) return;
    int beg = rowptr[v], end = rowptr[v + 1];
    float acc = 0.f;
    int e = beg;
    for (; e + 4 <= end; e += 4) {
        int s0 = csr_src[e], s1 = csr_src[e + 1], s2 = csr_src[e + 2], s3 = csr_src[e + 3];
        acc += hw[(size_t)s0 * 16 + f] + hw[(size_t)s1 * 16 + f] + hw[(size_t)s2 * 16 + f] + hw[(size_t)s3 * 16 + f];
    }
    for (; e < end; ++e) acc += hw[(size_t)csr_src[e] * 16 + f];
    float o = acc * dstn[v] + bias[f];
    o = 1.f / (1.f + __expf(-o)) + 1e-8f;   // sigmoid + 1e-8
    out[(size_t)v * 16 + f] = o;
}

extern "C" void kernel_launch(void* const* d_in, const int* in_sizes, int n_in,
                              void* d_out, int out_size, void* d_ws, size_t ws_size,
                              hipStream_t stream) {
    const float* features = (const float*)d_in[0];
    const int*   src      = (const int*)d_in[1];
    const int*   dst      = (const int*)d_in[2];
    const float* W0       = (const float*)d_in[3];
    const float* b0       = (const float*)d_in[4];
    const float* W1       = (const float*)d_in[5];
    const float* b1       = (const float*)d_in[6];
    const float* W2       = (const float*)d_in[7];
    const float* b2       = (const float*)d_in[8];
    float* out = (float*)d_out;

    const int N = in_sizes[0] / 128;
    const int E = in_sizes[1];

    char* ws = (char*)d_ws;
    size_t off = 0;
    auto alloc = [&](size_t bytes) -> char* {
        char* p = ws + off;
        off += (bytes + 255) / 256 * 256;
        return p;
    };
    int*   outdeg = (int*)alloc((size_t)N * 4);
    int*   indeg  = (int*)alloc((size_t)N * 4);
    float* srcn   = (float*)alloc((size_t)N * 4);
    float* dstn   = (float*)alloc((size_t)N * 4);
    int*   rowptr = (int*)alloc((size_t)(N + 1) * 4);
    int*   cursor = (int*)alloc((size_t)N * 4);
    int*   bsum   = (int*)alloc(512 * 4);
    int*   bscan  = (int*)alloc(512 * 4);
    int*   csr    = (int*)alloc((size_t)E * 4);
    float* Hbuf   = (float*)alloc((size_t)N * 128 * 4);
    float* HWbuf  = (float*)alloc((size_t)N * 128 * 4);
    (void)ws_size; (void)n_in; (void)out_size;

    hipMemsetAsync(outdeg, 0, (size_t)N * 4, stream);
    hipMemsetAsync(indeg, 0, (size_t)N * 4, stream);

    int eb = (E + BLK - 1) / BLK;
    int nb = (N + BLK - 1) / BLK;

    k_degrees<<<eb, BLK, 0, stream>>>(src, dst, outdeg, indeg, E);
    k_norms<<<nb, BLK, 0, stream>>>(outdeg, indeg, srcn, dstn, N);
    k_blocksum<<<nb, BLK, 0, stream>>>(indeg, bsum, N);
    k_scan_bsum<<<1, 512, 0, stream>>>(bsum, bscan, nb);
    k_scan_scatter<<<nb, BLK, 0, stream>>>(indeg, bscan, rowptr, cursor, N);
    k_fill_csr<<<eb, BLK, 0, stream>>>(src, dst, cursor, csr, E);

    // layer 0: features -> HWbuf -> Hbuf (relu)
    k_gemm128<<<(N + 63) / 64, 256, 0, stream>>>(features, W0, srcn, HWbuf, N);
    k_agg128<0><<<(N + 3) / 4, 256, 0, stream>>>(HWbuf, rowptr, csr, dstn, b0, Hbuf, N);
    // layer 1: Hbuf -> HWbuf -> Hbuf (relu)
    k_gemm128<<<(N + 63) / 64, 256, 0, stream>>>(Hbuf, W1, srcn, HWbuf, N);
    k_agg128<0><<<(N + 3) / 4, 256, 0, stream>>>(HWbuf, rowptr, csr, dstn, b1, Hbuf, N);
    // layer 2: Hbuf -> HWbuf(16) -> out (sigmoid + 1e-8)
    k_gemm16<<<(N + 127) / 128, 256, 0, stream>>>(Hbuf, W2, srcn, HWbuf, N);
    k_agg16<<<((size_t)N * 16 + BLK - 1) / BLK, BLK, 0, stream>>>(HWbuf, rowptr, csr, dstn, b2, out, N);
}

// Round 2
// 521.865 us; speedup vs baseline: 1.4228x; 1.4228x over previous
//
#include <hip/hip_runtime.h>
#include <hip/hip_bf16.h>

// GCN 3-layer GraphConv, R2:
//  - CSR fill without atomics (per-edge offset captured in degree pass)
//  - all activations/hw buffers bf16; gather kernel = 4 edge-groups x 16 lanes,
//    unroll 4 -> 16 rows in flight per wave; shfl_xor cross-group reduce
//  - GEMMs via mfma_f32_16x16x32_bf16 (A/B loaded with one consistent k-bijection;
//    C/D layout per verified col=lane&15,row=(lane>>4)*4+i)
//  - layer 2 reordered: agg(128) first, then 128->16 GEMM w/ fused bias+sigmoid

constexpr int BLK = 256;

typedef __attribute__((ext_vector_type(8))) short s8v;
typedef __attribute__((ext_vector_type(4))) float f4v;

__device__ __forceinline__ float bflo(unsigned int u) { return __uint_as_float(u << 16); }
__device__ __forceinline__ float bfhi(unsigned int u) { return __uint_as_float(u & 0xffff0000u); }
__device__ __forceinline__ unsigned int bfr(float f) {  // round-to-nearest-even bf16 (as low 16 bits)
    unsigned int u = __float_as_uint(f);
    return (u + 0x7fffu + ((u >> 16) & 1u)) >> 16;
}
__device__ __forceinline__ unsigned int bfpack(float lo, float hi) {
    unsigned int ul = __float_as_uint(lo), uh = __float_as_uint(hi);
    unsigned int rl = (ul + 0x7fffu + ((ul >> 16) & 1u)) >> 16;
    unsigned int rh = (uh + 0x7fffu + ((uh >> 16) & 1u)) & 0xffff0000u;
    return rl | rh;
}

// ---------------- degrees (+ per-edge CSR slot) ----------------
__global__ void k_degrees(const int* __restrict__ src, const int* __restrict__ dst,
                          int* __restrict__ outdeg, int* __restrict__ indeg,
                          int* __restrict__ eoff, int E) {
    int e = blockIdx.x * blockDim.x + threadIdx.x;
    if (e < E) {
        atomicAdd(&outdeg[src[e]], 1);
        eoff[e] = atomicAdd(&indeg[dst[e]], 1);
    }
}

__global__ void k_norms(const int* __restrict__ outdeg, const int* __restrict__ indeg,
                        float* __restrict__ srcn, float* __restrict__ dstn, int N) {
    int i = blockIdx.x * blockDim.x + threadIdx.x;
    if (i < N) {
        int od = outdeg[i]; if (od < 1) od = 1;
        int id = indeg[i];  if (id < 1) id = 1;
        srcn[i] = rsqrtf((float)od);
        dstn[i] = rsqrtf((float)id);
    }
}

// ---------------- CSR rowptr: blocksum -> scan -> local scan ----------------
__global__ void k_blocksum(const int* __restrict__ counts, int* __restrict__ bsum, int N) {
    __shared__ int sdata[BLK];
    int i = blockIdx.x * BLK + threadIdx.x;
    sdata[threadIdx.x] = (i < N) ? counts[i] : 0;
    __syncthreads();
    for (int s = BLK / 2; s > 0; s >>= 1) {
        if (threadIdx.x < s) sdata[threadIdx.x] += sdata[threadIdx.x + s];
        __syncthreads();
    }
    if (threadIdx.x == 0) bsum[blockIdx.x] = sdata[0];
}

__global__ void k_scan_bsum(const int* __restrict__ bsum, int* __restrict__ bscan, int nb) {
    __shared__ int s[512];
    int t = threadIdx.x;
    s[t] = (t < nb) ? bsum[t] : 0;
    __syncthreads();
    for (int d = 1; d < 512; d <<= 1) {
        int x = (t >= d) ? s[t - d] : 0;
        __syncthreads();
        s[t] += x;
        __syncthreads();
    }
    bscan[t] = (t > 0) ? s[t - 1] : 0;
}

__global__ void k_scan_scatter(const int* __restrict__ counts, const int* __restrict__ bscan,
                               int* __restrict__ rowptr, int N) {
    __shared__ int s[BLK];
    int i = blockIdx.x * BLK + threadIdx.x;
    int c = (i < N) ? counts[i] : 0;
    s[threadIdx.x] = c;
    __syncthreads();
    for (int d = 1; d < BLK; d <<= 1) {
        int x = (threadIdx.x >= d) ? s[threadIdx.x - d] : 0;
        __syncthreads();
        s[threadIdx.x] += x;
        __syncthreads();
    }
    if (i < N) {
        int excl = bscan[blockIdx.x] + s[threadIdx.x] - c;
        rowptr[i] = excl;
        if (i == N - 1) rowptr[N] = excl + c;
    }
}

__global__ void k_fill2(const int* __restrict__ src, const int* __restrict__ dst,
                        const int* __restrict__ eoff, const int* __restrict__ rowptr,
                        int* __restrict__ csr, int E) {
    int e = blockIdx.x * blockDim.x + threadIdx.x;
    if (e < E) csr[rowptr[dst[e]] + eoff[e]] = src[e];
}

// ---------------- weight transpose + bf16 ----------------
__global__ void k_wt(const float* __restrict__ W, unsigned short* __restrict__ Wt, int total) {
    // Wt[c][k] = bf16(W[k][c]); K = 128 fixed. total = 128 * Ncol
    int i = blockIdx.x * blockDim.x + threadIdx.x;
    if (i < total) {
        int c = i >> 7, k = i & 127;
        int Ncol = total >> 7;
        Wt[i] = (unsigned short)bfr(W[k * Ncol + c]);
    }
}

// ---------------- A0 = bf16(features * srcn) ----------------
__global__ void k_prep(const float* __restrict__ F, const float* __restrict__ srcn,
                       unsigned short* __restrict__ A0, int N) {
    int i = blockIdx.x * blockDim.x + threadIdx.x;   // one 8-elem chunk
    if (i >= N * 16) return;
    int row = i >> 4;
    float s = srcn[row];
    const float4* p = (const float4*)(F + (size_t)i * 8);
    float4 a = p[0], b = p[1];
    uint4 o;
    o.x = bfpack(a.x * s, a.y * s);
    o.y = bfpack(a.z * s, a.w * s);
    o.z = bfpack(b.x * s, b.y * s);
    o.w = bfpack(b.z * s, b.w * s);
    *(uint4*)(A0 + (size_t)i * 8) = o;
}

// ---------------- MFMA GEMM: out[M x NT*16] = A[M x 128] @ Wt^T ----------------
// A row-major bf16; Wt[col][k] bf16. EPI 0: store bf16. EPI 1: +bias, sigmoid, fp32 out.
template <int NT, int EPI>
__global__ __launch_bounds__(256) void k_gemm_mfma(const unsigned short* __restrict__ A,
                                                   const unsigned short* __restrict__ Wt,
                                                   const float* __restrict__ bias,
                                                   unsigned short* __restrict__ outb,
                                                   float* __restrict__ outf, int M) {
    __shared__ unsigned short As[64 * 128];
    __shared__ unsigned short Ws[NT * 16 * 128];
    int tx = threadIdx.x;
    int row0 = blockIdx.x * 64;
    // stage Wt (NT*16 rows x 16 chunks of 16B), XOR chunk-swizzle by row&7
    for (int p = 0; p < NT; ++p) {
        int r = p * 16 + (tx >> 4);
        int c = tx & 15;
        int cs = c ^ (r & 7);
        *(uint4*)(&Ws[(r * 16 + cs) * 8]) = *(const uint4*)(Wt + (size_t)r * 128 + c * 8);
    }
    // stage A (64 rows x 16 chunks)
    for (int p = 0; p < 4; ++p) {
        int r = p * 16 + (tx >> 4);
        int c = tx & 15;
        int cs = c ^ (r & 7);
        int gr = row0 + r;
        uint4 v = make_uint4(0u, 0u, 0u, 0u);
        if (gr < M) v = *(const uint4*)(A + (size_t)gr * 128 + c * 8);
        *(uint4*)(&As[(r * 16 + cs) * 8]) = v;
    }
    __syncthreads();

    int w = tx >> 6, l = tx & 63;
    int lr = l & 15, lg = l >> 4;
    f4v acc[NT];
#pragma unroll
    for (int nt = 0; nt < NT; ++nt) { acc[nt][0] = 0.f; acc[nt][1] = 0.f; acc[nt][2] = 0.f; acc[nt][3] = 0.f; }

    int ar = w * 16 + lr;
#pragma unroll
    for (int kk = 0; kk < 4; ++kk) {
        s8v af = *(const s8v*)(&As[(ar * 16 + ((kk * 4 + lg) ^ (ar & 7))) * 8]);
#pragma unroll
        for (int nt = 0; nt < NT; ++nt) {
            int br = nt * 16 + lr;
            s8v bf = *(const s8v*)(&Ws[(br * 16 + ((kk * 4 + lg) ^ (br & 7))) * 8]);
            acc[nt] = __builtin_amdgcn_mfma_f32_16x16x32_bf16(af, bf, acc[nt], 0, 0, 0);
        }
    }
    // epilogue: D row = lg*4+i, col = lr (verified mapping)
#pragma unroll
    for (int nt = 0; nt < NT; ++nt) {
#pragma unroll
        for (int i = 0; i < 4; ++i) {
            int R = row0 + w * 16 + lg * 4 + i;
            if (R < M) {
                int col = nt * 16 + lr;
                float v = acc[nt][i];
                if (EPI == 0) {
                    outb[(size_t)R * 128 + col] = (unsigned short)bfr(v);
                } else {
                    v += bias[col];
                    v = 1.f / (1.f + __expf(-v)) + 1e-8f;
                    outf[(size_t)R * 16 + col] = v;
                }
            }
        }
    }
}

// ---------------- aggregation: wave per node, 4 edge-groups x 16 lanes ----------------
// EPI 0: out = bf16(relu(sum*dstn + bias) * srcn)   (feeds next GEMM pre-scaled)
// EPI 1: out = bf16(sum*dstn)                        (layer-2 pre-GEMM aggregate)
template <int EPI>
__global__ __launch_bounds__(256) void k_agg(const unsigned short* __restrict__ hw,
                                             const int* __restrict__ rowptr,
                                             const int* __restrict__ csr,
                                             const float* __restrict__ dstn,
                                             const float* __restrict__ bias,
                                             const float* __restrict__ srcn,
                                             unsigned short* __restrict__ out, int N) {
    int node = blockIdx.x * 4 + (threadIdx.x >> 6);
    if (node >= N) return;
    int l64 = threadIdx.x & 63;
    int g = l64 >> 4;        // edge group 0..3
    int l = l64 & 15;        // feature sub-lane: features l*8 .. l*8+7
    int beg = rowptr[node], end = rowptr[node + 1];

    float a0 = 0.f, a1 = 0.f, a2 = 0.f, a3 = 0.f, a4 = 0.f, a5 = 0.f, a6 = 0.f, a7 = 0.f;

#define ACC8(V)                                                   \
    a0 += bflo(V.x); a1 += bfhi(V.x); a2 += bflo(V.y); a3 += bfhi(V.y); \
    a4 += bflo(V.z); a5 += bfhi(V.z); a6 += bflo(V.w); a7 += bfhi(V.w);

    int e = beg + g;
    for (; e + 12 < end; e += 16) {   // 4 edges per group in flight
        int s0 = csr[e], s1 = csr[e + 4], s2 = csr[e + 8], s3 = csr[e + 12];
        uint4 v0 = *(const uint4*)(hw + (size_t)s0 * 128 + l * 8);
        uint4 v1 = *(const uint4*)(hw + (size_t)s1 * 128 + l * 8);
        uint4 v2 = *(const uint4*)(hw + (size_t)s2 * 128 + l * 8);
        uint4 v3 = *(const uint4*)(hw + (size_t)s3 * 128 + l * 8);
        ACC8(v0) ACC8(v1) ACC8(v2) ACC8(v3)
    }
    for (; e < end; e += 4) {
        int s0 = csr[e];
        uint4 v0 = *(const uint4*)(hw + (size_t)s0 * 128 + l * 8);
        ACC8(v0)
    }
#undef ACC8

    // cross-group reduce (groups hold disjoint edges, same features)
    a0 += __shfl_xor(a0, 16, 64); a0 += __shfl_xor(a0, 32, 64);
    a1 += __shfl_xor(a1, 16, 64); a1 += __shfl_xor(a1, 32, 64);
    a2 += __shfl_xor(a2, 16, 64); a2 += __shfl_xor(a2, 32, 64);
    a3 += __shfl_xor(a3, 16, 64); a3 += __shfl_xor(a3, 32, 64);
    a4 += __shfl_xor(a4, 16, 64); a4 += __shfl_xor(a4, 32, 64);
    a5 += __shfl_xor(a5, 16, 64); a5 += __shfl_xor(a5, 32, 64);
    a6 += __shfl_xor(a6, 16, 64); a6 += __shfl_xor(a6, 32, 64);
    a7 += __shfl_xor(a7, 16, 64); a7 += __shfl_xor(a7, 32, 64);

    if (g == 0) {
        float dn = dstn[node];
        float o0 = a0 * dn, o1 = a1 * dn, o2 = a2 * dn, o3 = a3 * dn;
        float o4 = a4 * dn, o5 = a5 * dn, o6 = a6 * dn, o7 = a7 * dn;
        if (EPI == 0) {
            float4 b0 = *(const float4*)(bias + l * 8);
            float4 b1 = *(const float4*)(bias + l * 8 + 4);
            float sn = srcn[node];
            o0 = fmaxf(o0 + b0.x, 0.f) * sn; o1 = fmaxf(o1 + b0.y, 0.f) * sn;
            o2 = fmaxf(o2 + b0.z, 0.f) * sn; o3 = fmaxf(o3 + b0.w, 0.f) * sn;
            o4 = fmaxf(o4 + b1.x, 0.f) * sn; o5 = fmaxf(o5 + b1.y, 0.f) * sn;
            o6 = fmaxf(o6 + b1.z, 0.f) * sn; o7 = fmaxf(o7 + b1.w, 0.f) * sn;
        }
        uint4 o;
        o.x = bfpack(o0, o1); o.y = bfpack(o2, o3);
        o.z = bfpack(o4, o5); o.w = bfpack(o6, o7);
        *(uint4*)(out + (size_t)node * 128 + l * 8) = o;
    }
}

extern "C" void kernel_launch(void* const* d_in, const int* in_sizes, int n_in,
                              void* d_out, int out_size, void* d_ws, size_t ws_size,
                              hipStream_t stream) {
    const float* features = (const float*)d_in[0];
    const int*   src      = (const int*)d_in[1];
    const int*   dst      = (const int*)d_in[2];
    const float* W0       = (const float*)d_in[3];
    const float* b0       = (const float*)d_in[4];
    const float* W1       = (const float*)d_in[5];
    const float* b1       = (const float*)d_in[6];
    const float* W2       = (const float*)d_in[7];
    const float* b2       = (const float*)d_in[8];
    float* out = (float*)d_out;

    const int N = in_sizes[0] / 128;
    const int E = in_sizes[1];

    char* ws = (char*)d_ws;
    size_t off = 0;
    auto alloc = [&](size_t bytes) -> char* {
        char* p = ws + off;
        off += (bytes + 255) / 256 * 256;
        return p;
    };
    int*   outdeg = (int*)alloc((size_t)N * 4);
    int*   indeg  = (int*)alloc((size_t)N * 4);
    float* srcn   = (float*)alloc((size_t)N * 4);
    float* dstn   = (float*)alloc((size_t)N * 4);
    int*   rowptr = (int*)alloc((size_t)(N + 1) * 4);
    int*   bsum   = (int*)alloc(512 * 4);
    int*   bscan  = (int*)alloc(512 * 4);
    int*   eoff   = (int*)alloc((size_t)E * 4);
    int*   csr    = (int*)alloc((size_t)E * 4);
    unsigned short* Wt0 = (unsigned short*)alloc(128 * 128 * 2);
    unsigned short* Wt1 = (unsigned short*)alloc(128 * 128 * 2);
    unsigned short* Wt2 = (unsigned short*)alloc(16 * 128 * 2);
    unsigned short* B1 = (unsigned short*)alloc((size_t)N * 128 * 2);
    unsigned short* B2 = (unsigned short*)alloc((size_t)N * 128 * 2);
    unsigned short* B3 = (unsigned short*)alloc((size_t)N * 128 * 2);
    (void)ws_size; (void)n_in; (void)out_size;

    hipMemsetAsync(outdeg, 0, (size_t)N * 4, stream);
    hipMemsetAsync(indeg, 0, (size_t)N * 4, stream);

    int eb = (E + BLK - 1) / BLK;
    int nb = (N + BLK - 1) / BLK;

    k_degrees<<<eb, BLK, 0, stream>>>(src, dst, outdeg, indeg, eoff, E);
    k_norms<<<nb, BLK, 0, stream>>>(outdeg, indeg, srcn, dstn, N);
    k_blocksum<<<nb, BLK, 0, stream>>>(indeg, bsum, N);
    k_scan_bsum<<<1, 512, 0, stream>>>(bsum, bscan, nb);
    k_scan_scatter<<<nb, BLK, 0, stream>>>(indeg, bscan, rowptr, N);
    k_fill2<<<eb, BLK, 0, stream>>>(src, dst, eoff, rowptr, csr, E);

    k_wt<<<64, BLK, 0, stream>>>(W0, Wt0, 128 * 128);
    k_wt<<<64, BLK, 0, stream>>>(W1, Wt1, 128 * 128);
    k_wt<<<8, BLK, 0, stream>>>(W2, Wt2, 16 * 128);
    k_prep<<<(N * 16 + BLK - 1) / BLK, BLK, 0, stream>>>(features, srcn, B1, N);

    int gb = (N + 63) / 64;     // gemm blocks
    int ab = (N + 3) / 4;       // agg blocks

    // layer 0
    k_gemm_mfma<8, 0><<<gb, 256, 0, stream>>>(B1, Wt0, nullptr, B2, nullptr, N);
    k_agg<0><<<ab, 256, 0, stream>>>(B2, rowptr, csr, dstn, b0, srcn, B3, N);
    // layer 1
    k_gemm_mfma<8, 0><<<gb, 256, 0, stream>>>(B3, Wt1, nullptr, B2, nullptr, N);
    k_agg<0><<<ab, 256, 0, stream>>>(B2, rowptr, csr, dstn, b1, srcn, B1, N);
    // layer 2: aggregate first (linearity), then 128->16 GEMM with bias+sigmoid
    k_agg<1><<<ab, 256, 0, stream>>>(B1, rowptr, csr, dstn, nullptr, nullptr, B3, N);
    k_gemm_mfma<1, 1><<<gb, 256, 0, stream>>>(B3, Wt2, b2, nullptr, out, N);
}